// Round 1
// baseline (652.706 us; speedup 1.0000x reference)
//
#include <hip/hip_runtime.h>

#define T_N   1024
#define B_N   64
#define CIN   32
#define COUT  32
#define MODES 16
#define DT    0.01f
#define PI_F  3.14159265358979323846f

// ---------------------------------------------------------------------------
// Radix-2 Stockham FFT, length 1024, natural-order in/out, LDS ping-pong.
// 256 threads, 2 butterflies per thread per stage, 10 stages. Result in A.
// ---------------------------------------------------------------------------
template <int SIGN>
__device__ __forceinline__ void fft1024(float2* A, float2* B, int tid) {
    float2* src = A;
    float2* dst = B;
    int l = 512, m = 1;
#pragma unroll
    for (int s = 0; s < 10; ++s) {
        __syncthreads();
#pragma unroll
        for (int r = 0; r < 2; ++r) {
            int idx = tid + (r << 8);            // 0..511
            int k = idx & (m - 1);
            int j = idx >> s;                    // m == 1<<s
            float2 c0 = src[k + j * m];
            float2 c1 = src[k + j * m + 512];    // l*m == 512 always
            float ang = (float)SIGN * PI_F * (float)j / (float)l;
            float sw, cw;
            __sincosf(ang, &sw, &cw);
            float ex = c0.x - c1.x, ey = c0.y - c1.y;
            dst[k + 2 * j * m]     = make_float2(c0.x + c1.x, c0.y + c1.y);
            dst[k + 2 * j * m + m] = make_float2(cw * ex - sw * ey, cw * ey + sw * ex);
        }
        float2* t = src; src = dst; dst = t;
        l >>= 1; m <<= 1;
    }
    __syncthreads();
}

// ---------------------------------------------------------------------------
// Kernel A: forward FFT of each (b,i) row of x -> alpha[b][i][x] (float2)
// ---------------------------------------------------------------------------
__global__ __launch_bounds__(256) void k_fft_fwd(const float* __restrict__ x,
                                                 float2* __restrict__ alpha) {
    __shared__ float2 A[1024];
    __shared__ float2 Bb[1024];
    int row = blockIdx.x;                 // b*CIN + i
    int tid = threadIdx.x;
    const float* xr = x + (size_t)row * T_N;
#pragma unroll
    for (int r = 0; r < 4; ++r) {
        int j = tid + (r << 8);
        A[j] = make_float2(xr[j], 0.0f);
    }
    fft1024<-1>(A, Bb, tid);
    float2* outp = alpha + (size_t)row * T_N;
#pragma unroll
    for (int r = 0; r < 4; ++r) {
        int j = tid + (r << 8);
        outp[j] = A[j];
    }
}

// ---------------------------------------------------------------------------
// Kernel C: per-frequency mixing.
// out1[b,o,x] = sum_i alpha[b,i,x] * Hsum[x,i,o],
// Hsum[x,i,o] = sum_k res[i,o,k] / (i*w[x] - pole[i,o,k])   (computed inline)
// One block per frequency x.
// ---------------------------------------------------------------------------
__global__ __launch_bounds__(256) void k_out1(const float2* __restrict__ alpha,
                                              const float* __restrict__ pr,
                                              const float* __restrict__ pim,
                                              const float* __restrict__ rr,
                                              const float* __restrict__ ri,
                                              float2* __restrict__ out1) {
    __shared__ float2 Hs[CIN][COUT];   // 8 KB
    __shared__ float2 Asl[B_N][CIN];   // 16 KB
    int x = blockIdx.x;
    int tid = threadIdx.x;

    // stage alpha slice [b][i] for this x (scattered 8B reads)
#pragma unroll
    for (int r = 0; r < 8; ++r) {
        int e = tid + (r << 8);        // 0..2047
        int b = e >> 5, i = e & 31;
        Asl[b][i] = alpha[((size_t)(b * CIN + i)) * T_N + x];
    }

    int fx = x - ((x >= 512) ? 1024 : 0);
    float w = (float)fx * (2.0f * PI_F / (T_N * DT));
#pragma unroll
    for (int r = 0; r < 4; ++r) {
        int e = tid + (r << 8);        // 0..1023 -> (i,o)
        int i = e >> 5, o = e & 31;
        int base = (i * COUT + o) * MODES;
        float hr = 0.f, hi = 0.f;
#pragma unroll
        for (int k = 0; k < MODES; ++k) {
            float a = pr[base + k], bI = pim[base + k];
            float d = w - bI;
            float inv = 1.0f / (a * a + d * d);
            float vR = -a * inv, vI = -d * inv;          // 1/(iw - pole)
            float sR = rr[base + k], sI = ri[base + k];
            hr += sR * vR - sI * vI;
            hi += sR * vI + sI * vR;
        }
        Hs[i][o] = make_float2(hr, hi);
    }
    __syncthreads();

    int o = tid & 31, bg = tid >> 5;   // 8 b-groups of 8
    float2 acc[8];
#pragma unroll
    for (int bb = 0; bb < 8; ++bb) acc[bb] = make_float2(0.f, 0.f);
    for (int i = 0; i < CIN; ++i) {
        float2 h = Hs[i][o];
#pragma unroll
        for (int bb = 0; bb < 8; ++bb) {
            float2 a = Asl[bg * 8 + bb][i];
            acc[bb].x += a.x * h.x - a.y * h.y;
            acc[bb].y += a.x * h.y + a.y * h.x;
        }
    }
#pragma unroll
    for (int bb = 0; bb < 8; ++bb) {
        int b = bg * 8 + bb;
        out1[((size_t)(b * COUT + o)) * T_N + x] = acc[bb];
    }
}

// ---------------------------------------------------------------------------
// Kernel D: out2[b,o,k] = -sum_i sum_x alpha[b,i,x]*res[i,o,k]/(i*w[x]-pole)
// One block per (i,o) pair; atomic accumulation over i into o2re/o2im.
// ---------------------------------------------------------------------------
__global__ __launch_bounds__(256) void k_out2(const float2* __restrict__ alpha,
                                              const float* __restrict__ pr,
                                              const float* __restrict__ pim,
                                              const float* __restrict__ rr,
                                              const float* __restrict__ ri,
                                              float* __restrict__ o2re,
                                              float* __restrict__ o2im) {
    __shared__ float aRe[64][65];      // [xx][b], padded: conflict-free
    __shared__ float aIm[64][65];
    __shared__ float vRe[16][64];      // folded -res*invd, [k][xx]
    __shared__ float vIm[16][64];
    int blk = blockIdx.x;              // i*32 + o
    int i = blk >> 5, o = blk & 31;
    int tid = threadIdx.x;
    int lane = tid & 63, wid = tid >> 6;
    int pbase = (i * COUT + o) * MODES;

    float accR[4] = {0.f, 0.f, 0.f, 0.f};
    float accI[4] = {0.f, 0.f, 0.f, 0.f};

    for (int xt = 0; xt < 16; ++xt) {
        __syncthreads();
        // stage alpha tile: 64 b x 64 xx (coalesced reads, padded LDS writes)
#pragma unroll
        for (int r = 0; r < 16; ++r) {
            int e = tid + (r << 8);    // 0..4095
            int b = e >> 6, xx = e & 63;
            float2 a = alpha[((size_t)(b * CIN + i)) * T_N + xt * 64 + xx];
            aRe[xx][b] = a.x;
            aIm[xx][b] = a.y;
        }
        // folded factor: v[k][xx] = -res[i,o,k] / (i*w[x] - pole[i,o,k])
#pragma unroll
        for (int r = 0; r < 4; ++r) {
            int e = tid + (r << 8);    // 0..1023
            int k = e >> 6, xx = e & 63;
            int xg = xt * 64 + xx;
            int fx = xg - ((xg >= 512) ? 1024 : 0);
            float w = (float)fx * (2.0f * PI_F / (T_N * DT));
            float a = pr[pbase + k], bI = pim[pbase + k];
            float d = w - bI;
            float inv = 1.0f / (a * a + d * d);
            float uR = -a * inv, uI = -d * inv;
            float sR = rr[pbase + k], sI = ri[pbase + k];
            vRe[k][xx] = -(sR * uR - sI * uI);
            vIm[k][xx] = -(sR * uI + sI * uR);
        }
        __syncthreads();

        int b = lane;
        for (int xx = 0; xx < 64; ++xx) {
            float aR = aRe[xx][b], aI = aIm[xx][b];
#pragma unroll
            for (int kk = 0; kk < 4; ++kk) {
                int k = wid * 4 + kk;
                float mR = vRe[k][xx], mI = vIm[k][xx];
                accR[kk] += aR * mR - aI * mI;
                accI[kk] += aR * mI + aI * mR;
            }
        }
    }
#pragma unroll
    for (int kk = 0; kk < 4; ++kk) {
        int k = wid * 4 + kk;
        int idx = (lane * COUT + o) * MODES + k;   // [b][o][k]
        atomicAdd(&o2re[idx], accR[kk]);
        atomicAdd(&o2im[idx], accI[kk]);
    }
}

// ---------------------------------------------------------------------------
// Kernel IFFT: x1 = Re(ifft(out1)) = Re(fft_{+}(out1))/n, per (b,o) row.
// Writes d_out (fully).
// ---------------------------------------------------------------------------
__global__ __launch_bounds__(256) void k_ifft(const float2* __restrict__ out1,
                                              float* __restrict__ outp) {
    __shared__ float2 A[1024];
    __shared__ float2 Bb[1024];
    int row = blockIdx.x;              // b*COUT + o
    int tid = threadIdx.x;
    const float2* src = out1 + (size_t)row * T_N;
#pragma unroll
    for (int r = 0; r < 4; ++r) {
        int j = tid + (r << 8);
        A[j] = src[j];
    }
    fft1024<1>(A, Bb, tid);
    float* dst = outp + (size_t)row * T_N;
    const float inv_n = 1.0f / (float)T_N;
#pragma unroll
    for (int r = 0; r < 4; ++r) {
        int j = tid + (r << 8);
        dst[j] = A[j].x * inv_n;
    }
}

// ---------------------------------------------------------------------------
// Kernel X2: out[b,o,z] += (1/n)*Re( sum_{c,m} out2[b,c,m]*exp(pole[c,o,m]*t_z) )
// One block per (o, z-tile of 64).
// ---------------------------------------------------------------------------
__global__ __launch_bounds__(256) void k_x2(const float* __restrict__ o2re,
                                            const float* __restrict__ o2im,
                                            const float* __restrict__ pr,
                                            const float* __restrict__ pim,
                                            float* __restrict__ outp) {
    __shared__ float Ere[32][64];      // [j][z]
    __shared__ float Eim[32][64];
    __shared__ float Pre[64][32];      // out2 tile [b][j]
    __shared__ float Pim[64][32];
    int blk = blockIdx.x;              // o*16 + zt
    int o = blk >> 4, zt = blk & 15;
    int tid = threadIdx.x;
    int z = tid & 63, bg = tid >> 6;   // 4 b-groups of 16

    float acc[16];
#pragma unroll
    for (int q = 0; q < 16; ++q) acc[q] = 0.f;

    for (int cmt = 0; cmt < 16; ++cmt) {
        __syncthreads();
        // stage out2 tile (b x 32 cm)
#pragma unroll
        for (int r = 0; r < 8; ++r) {
            int e = tid + (r << 8);    // 0..2047
            int b = e >> 5, j = e & 31;
            int cm = cmt * 32 + j;
            Pre[b][j] = o2re[b * 512 + cm];
            Pim[b][j] = o2im[b * 512 + cm];
        }
        // compute E tile: exp(pole[c,o,m]*t_z)
#pragma unroll
        for (int r = 0; r < 8; ++r) {
            int e = tid + (r << 8);    // 0..2047
            int j = e >> 6, zz = e & 63;
            int cm = cmt * 32 + j;
            int c = cm >> 4, m = cm & 15;
            int pidx = (c * COUT + o) * MODES + m;
            float tz = (float)(zt * 64 + zz) * DT;
            float er = __expf(pr[pidx] * tz);
            float sn, cn;
            __sincosf(pim[pidx] * tz, &sn, &cn);
            Ere[j][zz] = er * cn;
            Eim[j][zz] = er * sn;
        }
        __syncthreads();

        for (int j = 0; j < 32; ++j) {
            float eR = Ere[j][z], eI = Eim[j][z];
#pragma unroll
            for (int q = 0; q < 16; ++q) {
                int b = bg * 16 + q;
                acc[q] += Pre[b][j] * eR - Pim[b][j] * eI;   // real part only
            }
        }
    }

    const float inv_n = 1.0f / (float)T_N;
#pragma unroll
    for (int q = 0; q < 16; ++q) {
        int b = bg * 16 + q;
        size_t idx = ((size_t)(b * COUT + o)) * T_N + zt * 64 + z;
        outp[idx] += acc[q] * inv_n;
    }
}

// ---------------------------------------------------------------------------
extern "C" void kernel_launch(void* const* d_in, const int* in_sizes, int n_in,
                              void* d_out, int out_size, void* d_ws, size_t ws_size,
                              hipStream_t stream) {
    const float* x   = (const float*)d_in[0];
    // d_in[1] = t (uniform grid; dt hard-coded, matches t[1]-t[0] exactly)
    const float* pr  = (const float*)d_in[2];
    const float* pim = (const float*)d_in[3];
    const float* rr  = (const float*)d_in[4];
    const float* ri  = (const float*)d_in[5];
    float* outp = (float*)d_out;

    char* ws = (char*)d_ws;
    const size_t ALPHA_BYTES = (size_t)B_N * CIN * T_N * sizeof(float2);  // 16 MB
    float2* alpha = (float2*)ws;
    float2* out1  = (float2*)(ws + ALPHA_BYTES);
    float*  o2re  = (float*)(ws + 2 * ALPHA_BYTES);
    float*  o2im  = (float*)(ws + 2 * ALPHA_BYTES + (size_t)B_N * COUT * MODES * sizeof(float));

    // zero out2 accumulators (deterministic per launch)
    hipMemsetAsync(o2re, 0, 2 * (size_t)B_N * COUT * MODES * sizeof(float), stream);

    k_fft_fwd<<<B_N * CIN, 256, 0, stream>>>(x, alpha);
    k_out1  <<<T_N, 256, 0, stream>>>(alpha, pr, pim, rr, ri, out1);
    k_out2  <<<CIN * COUT, 256, 0, stream>>>(alpha, pr, pim, rr, ri, o2re, o2im);
    k_ifft  <<<B_N * COUT, 256, 0, stream>>>(out1, outp);
    k_x2    <<<COUT * (T_N / 64), 256, 0, stream>>>(o2re, o2im, pr, pim, outp);
}

// Round 2
// 460.279 us; speedup vs baseline: 1.4181x; 1.4181x over previous
//
#include <hip/hip_runtime.h>

#define T_N   1024
#define B_N   64
#define CIN   32
#define COUT  32
#define MODES 16
#define DT    0.01f
#define PI_F  3.14159265358979323846f

// ---------------------------------------------------------------------------
// Radix-2 Stockham FFT, length 1024, natural-order in/out, LDS ping-pong.
// ---------------------------------------------------------------------------
template <int SIGN>
__device__ __forceinline__ void fft1024(float2* A, float2* B, int tid) {
    float2* src = A;
    float2* dst = B;
    int l = 512, m = 1;
#pragma unroll
    for (int s = 0; s < 10; ++s) {
        __syncthreads();
#pragma unroll
        for (int r = 0; r < 2; ++r) {
            int idx = tid + (r << 8);            // 0..511
            int k = idx & (m - 1);
            int j = idx >> s;                    // m == 1<<s
            float2 c0 = src[k + j * m];
            float2 c1 = src[k + j * m + 512];
            float ang = (float)SIGN * PI_F * (float)j / (float)l;
            float sw, cw;
            __sincosf(ang, &sw, &cw);
            float ex = c0.x - c1.x, ey = c0.y - c1.y;
            dst[k + 2 * j * m]     = make_float2(c0.x + c1.x, c0.y + c1.y);
            dst[k + 2 * j * m + m] = make_float2(cw * ex - sw * ey, cw * ey + sw * ex);
        }
        float2* t = src; src = dst; dst = t;
        l >>= 1; m <<= 1;
    }
    __syncthreads();
}

// ---------------------------------------------------------------------------
// forward FFT of each (b,i) row of x -> alpha[(b*CIN+i)][x]
// ---------------------------------------------------------------------------
__global__ __launch_bounds__(256) void k_fft_fwd(const float* __restrict__ x,
                                                 float2* __restrict__ alpha) {
    __shared__ float2 A[1024];
    __shared__ float2 Bb[1024];
    int row = blockIdx.x;
    int tid = threadIdx.x;
    const float* xr = x + (size_t)row * T_N;
#pragma unroll
    for (int r = 0; r < 4; ++r) {
        int j = tid + (r << 8);
        A[j] = make_float2(xr[j], 0.0f);
    }
    fft1024<-1>(A, Bb, tid);
    float2* outp = alpha + (size_t)row * T_N;
#pragma unroll
    for (int r = 0; r < 4; ++r) {
        int j = tid + (r << 8);
        outp[j] = A[j];
    }
}

// ---------------------------------------------------------------------------
// transpose alpha[(b*CIN+i)][x] -> alphaT[i][x][b]
// block = (i, xt): 32 x-tile by all 64 b
// ---------------------------------------------------------------------------
__global__ __launch_bounds__(256) void k_transpose_a(const float2* __restrict__ alpha,
                                                     float2* __restrict__ alphaT) {
    __shared__ float2 T[32 * 66];   // [xx][b], row 66 (pad 2): 2-way max
    int blk = blockIdx.x;
    int i = blk >> 5, xt = blk & 31;
    int tid = threadIdx.x;
#pragma unroll
    for (int r = 0; r < 8; ++r) {
        int e = tid + (r << 8);
        int xx = e & 31, b = e >> 5;
        T[xx * 66 + b] = alpha[((size_t)(b * CIN + i)) * T_N + xt * 32 + xx];
    }
    __syncthreads();
#pragma unroll
    for (int r = 0; r < 8; ++r) {
        int e = tid + (r << 8);
        int b = e & 63, xx = e >> 6;
        alphaT[((size_t)i * T_N + xt * 32 + xx) * B_N + b] = T[xx * 66 + b];
    }
}

// ---------------------------------------------------------------------------
// out1: per-frequency mixing; writes out1tmp[x][b*COUT+o] (coalesced)
// ---------------------------------------------------------------------------
__global__ __launch_bounds__(256) void k_out1(const float2* __restrict__ alphaT,
                                              const float* __restrict__ pr,
                                              const float* __restrict__ pim,
                                              const float* __restrict__ rr,
                                              const float* __restrict__ ri,
                                              float2* __restrict__ out1tmp) {
    __shared__ float2 Asl[32 * 64];   // [i][b]
    __shared__ float2 Hs[32 * 32];    // [i][o]
    int x = blockIdx.x;
    int tid = threadIdx.x;

#pragma unroll
    for (int r = 0; r < 8; ++r) {
        int e = tid + (r << 8);
        int b = e & 63, i = e >> 6;
        Asl[i * 64 + b] = alphaT[((size_t)i * T_N + x) * B_N + b];
    }

    int fx = x - ((x >= 512) ? 1024 : 0);
    float w = (float)fx * (2.0f * PI_F / (T_N * DT));
#pragma unroll
    for (int r = 0; r < 4; ++r) {
        int e = tid + (r << 8);
        int i = e >> 5, o = e & 31;
        int base = (i * COUT + o) * MODES;
        float hr = 0.f, hi = 0.f;
#pragma unroll
        for (int k = 0; k < MODES; ++k) {
            float a = pr[base + k], bI = pim[base + k];
            float d = w - bI;
            float inv = 1.0f / (a * a + d * d);
            float vR = -a * inv, vI = -d * inv;
            float sR = rr[base + k], sI = ri[base + k];
            hr += sR * vR - sI * vI;
            hi += sR * vI + sI * vR;
        }
        Hs[i * 32 + o] = make_float2(hr, hi);
    }
    __syncthreads();

    int o = tid & 31, bg = tid >> 5;
    float2 acc[8];
#pragma unroll
    for (int bb = 0; bb < 8; ++bb) acc[bb] = make_float2(0.f, 0.f);
    for (int i = 0; i < CIN; ++i) {
        float2 h = Hs[i * 32 + o];
#pragma unroll
        for (int bb = 0; bb < 8; ++bb) {
            float2 a = Asl[i * 64 + bg * 8 + bb];
            acc[bb].x += a.x * h.x - a.y * h.y;
            acc[bb].y += a.x * h.y + a.y * h.x;
        }
    }
#pragma unroll
    for (int bb = 0; bb < 8; ++bb) {
        out1tmp[(size_t)x * 2048 + (bg * 8 + bb) * 32 + o] = acc[bb];
    }
}

// ---------------------------------------------------------------------------
// out2 v2: block = (i, og of 4 o's, x-half). Thread owns 4b x 4k complex acc.
// Per xx: 4x ds_read_b128 + 64 FMA. Atomic accumulate into o2[b][o][k].
// ---------------------------------------------------------------------------
__global__ __launch_bounds__(256) void k_out2(const float4* __restrict__ alphaT4,
                                              const float* __restrict__ pr,
                                              const float* __restrict__ pim,
                                              const float* __restrict__ rr,
                                              const float* __restrict__ ri,
                                              float2* __restrict__ o2) {
    __shared__ float4 aT4[32 * 32];   // [xx][b-pair] 16 KB (linear stage)
    __shared__ float4 v4[4 * 32 * 8]; // [ol][xx][k-pair] 16 KB
    __shared__ float s_pr[64], s_pim[64], s_rr[64], s_ri[64];

    int blk = blockIdx.x;
    int i = blk >> 4, rem = blk & 15;
    int og = rem >> 1, xh = rem & 1;
    int tid = threadIdx.x;
    int ol = tid >> 6, lane = tid & 63;
    int bq = lane & 15, kq = lane >> 4;
    int o = og * 4 + ol;

    if (tid < 64) {
        int oo = tid >> 4, k = tid & 15;
        int pidx = (i * COUT + og * 4 + oo) * MODES + k;
        s_pr[tid] = pr[pidx]; s_pim[tid] = pim[pidx];
        s_rr[tid] = rr[pidx]; s_ri[tid] = ri[pidx];
    }

    float accR[4][4] = {}, accI[4][4] = {};
    const float w_scale = 2.0f * PI_F / (T_N * DT);
    float2* v2 = (float2*)v4;

    for (int xt = 0; xt < 16; ++xt) {
        int x0 = xh * 512 + xt * 32;
        __syncthreads();
        // linear stage of alphaT tile [x0..x0+31][all b]: 16 KB contiguous
        const float4* src = alphaT4 + ((size_t)i * (T_N * B_N / 2) + (size_t)x0 * (B_N / 2));
#pragma unroll
        for (int r = 0; r < 4; ++r) {
            int e = tid + (r << 8);
            aT4[e] = src[e];
        }
        // v[oo][xx][k] = -res/(i*w - pole)
#pragma unroll
        for (int r = 0; r < 8; ++r) {
            int e = tid + (r << 8);         // e = oo*512 + xx*16 + k
            int k = e & 15, xx = (e >> 4) & 31;
            int xg = x0 + xx;
            int fx = xg - ((xg >= 512) ? 1024 : 0);
            float w = (float)fx * w_scale;
            int pi_ = (e >> 9) * 16 + k;
            float a = s_pr[pi_], bI = s_pim[pi_];
            float d = w - bI;
            float inv = 1.0f / (a * a + d * d);
            float uR = -a * inv, uI = -d * inv;
            float sR = s_rr[pi_], sI = s_ri[pi_];
            v2[e] = make_float2(-(sR * uR - sI * uI), -(sR * uI + sI * uR));
        }
        __syncthreads();

        for (int xx = 0; xx < 32; ++xx) {
            float4 a0 = aT4[xx * 32 + bq * 2];
            float4 a1 = aT4[xx * 32 + bq * 2 + 1];
            float4 w0 = v4[ol * 256 + xx * 8 + kq * 2];
            float4 w1 = v4[ol * 256 + xx * 8 + kq * 2 + 1];
            float aR[4] = {a0.x, a0.z, a1.x, a1.z};
            float aI[4] = {a0.y, a0.w, a1.y, a1.w};
            float vR[4] = {w0.x, w0.z, w1.x, w1.z};
            float vI[4] = {w0.y, w0.w, w1.y, w1.w};
#pragma unroll
            for (int b_ = 0; b_ < 4; ++b_) {
#pragma unroll
                for (int k_ = 0; k_ < 4; ++k_) {
                    accR[b_][k_] += aR[b_] * vR[k_] - aI[b_] * vI[k_];
                    accI[b_][k_] += aR[b_] * vI[k_] + aI[b_] * vR[k_];
                }
            }
        }
    }

    int b0 = bq * 4, k0 = kq * 4;
#pragma unroll
    for (int b_ = 0; b_ < 4; ++b_) {
#pragma unroll
        for (int k_ = 0; k_ < 4; ++k_) {
            int idx = ((b0 + b_) * COUT + o) * MODES + k0 + k_;
            atomicAdd(&o2[idx].x, accR[b_][k_]);
            atomicAdd(&o2[idx].y, accI[b_][k_]);
        }
    }
}

// ---------------------------------------------------------------------------
// transpose out1tmp[x][bo] -> out1T[bo][x]
// ---------------------------------------------------------------------------
__global__ __launch_bounds__(256) void k_transpose_o1(const float2* __restrict__ out1tmp,
                                                      float2* __restrict__ out1T) {
    __shared__ float2 T[64 * 33];   // [j][xx], row 33
    int blk = blockIdx.x;
    int bot = blk >> 5, xt = blk & 31;
    int tid = threadIdx.x;
#pragma unroll
    for (int r = 0; r < 8; ++r) {
        int e = tid + (r << 8);
        int j = e & 63, xr = e >> 6;
        T[j * 33 + xr] = out1tmp[((size_t)(xt * 32 + xr)) * 2048 + bot * 64 + j];
    }
    __syncthreads();
#pragma unroll
    for (int r = 0; r < 8; ++r) {
        int e = tid + (r << 8);
        int xx = e & 31, j = e >> 5;
        out1T[((size_t)(bot * 64 + j)) * T_N + xt * 32 + xx] = T[j * 33 + xx];
    }
}

// ---------------------------------------------------------------------------
// x1 = Re(ifft(out1)) per (b,o) row; writes d_out fully.
// ---------------------------------------------------------------------------
__global__ __launch_bounds__(256) void k_ifft(const float2* __restrict__ out1T,
                                              float* __restrict__ outp) {
    __shared__ float2 A[1024];
    __shared__ float2 Bb[1024];
    int row = blockIdx.x;
    int tid = threadIdx.x;
    const float2* src = out1T + (size_t)row * T_N;
#pragma unroll
    for (int r = 0; r < 4; ++r) {
        int j = tid + (r << 8);
        A[j] = src[j];
    }
    fft1024<1>(A, Bb, tid);
    float* dst = outp + (size_t)row * T_N;
    const float inv_n = 1.0f / (float)T_N;
#pragma unroll
    for (int r = 0; r < 4; ++r) {
        int j = tid + (r << 8);
        dst[j] = A[j].x * inv_n;
    }
}

// ---------------------------------------------------------------------------
// x2 v2: block = (o, zt of 64 z). Thread owns 4b x 4z real acc.
// Per cm: 4x ds_read_b128 + 32 FMA.
// ---------------------------------------------------------------------------
__global__ __launch_bounds__(256) void k_x2(const float2* __restrict__ o2,
                                            const float* __restrict__ pr,
                                            const float* __restrict__ pim,
                                            float* __restrict__ outp) {
    __shared__ float4 P4[32 * 33];   // [j][b-pair], row 66 fl2 (pad 2, b128-aligned)
    __shared__ float4 E4[32 * 33];   // [j][z-pair]
    __shared__ float s_pr[512], s_pim[512];

    int blk = blockIdx.x;
    int o = blk >> 4, zt = blk & 15;
    int tid = threadIdx.x;
    int bq = tid & 15, zq = tid >> 4;
    int b0 = bq * 4, z0 = zq * 4;

#pragma unroll
    for (int r = 0; r < 2; ++r) {
        int e = tid + (r << 8);
        int c = e >> 4, m = e & 15;
        int pidx = (c * COUT + o) * MODES + m;
        s_pr[e] = pr[pidx];
        s_pim[e] = pim[pidx];
    }

    float acc[4][4] = {};
    float2* P2 = (float2*)P4;
    float2* E2 = (float2*)E4;

    for (int ct = 0; ct < 16; ++ct) {
        int cm0 = ct * 32;
        __syncthreads();
#pragma unroll
        for (int r = 0; r < 8; ++r) {
            int e = tid + (r << 8);
            int j = e & 31, b = e >> 5;
            P2[j * 66 + b] = o2[b * 512 + cm0 + j];
        }
#pragma unroll
        for (int r = 0; r < 8; ++r) {
            int e = tid + (r << 8);
            int z = e & 63, j = e >> 6;
            int cm = cm0 + j;
            float tz = (float)(zt * 64 + z) * DT;
            float er = __expf(s_pr[cm] * tz);
            float sn, cn;
            __sincosf(s_pim[cm] * tz, &sn, &cn);
            E2[j * 66 + z] = make_float2(er * cn, er * sn);
        }
        __syncthreads();

        for (int j = 0; j < 32; ++j) {
            float4 p0 = P4[j * 33 + bq * 2];
            float4 p1 = P4[j * 33 + bq * 2 + 1];
            float4 e0 = E4[j * 33 + zq * 2];
            float4 e1 = E4[j * 33 + zq * 2 + 1];
            float PRe[4] = {p0.x, p0.z, p1.x, p1.z};
            float PIm[4] = {p0.y, p0.w, p1.y, p1.w};
            float ERe[4] = {e0.x, e0.z, e1.x, e1.z};
            float EIm[4] = {e0.y, e0.w, e1.y, e1.w};
#pragma unroll
            for (int b_ = 0; b_ < 4; ++b_) {
#pragma unroll
                for (int z_ = 0; z_ < 4; ++z_) {
                    acc[b_][z_] += PRe[b_] * ERe[z_] - PIm[b_] * EIm[z_];
                }
            }
        }
    }

    const float inv_n = 1.0f / (float)T_N;
#pragma unroll
    for (int b_ = 0; b_ < 4; ++b_) {
#pragma unroll
        for (int z_ = 0; z_ < 4; ++z_) {
            size_t idx = (size_t)(b0 + b_) * (COUT * T_N) + (size_t)o * T_N + zt * 64 + z0 + z_;
            outp[idx] += acc[b_][z_] * inv_n;
        }
    }
}

// ---------------------------------------------------------------------------
extern "C" void kernel_launch(void* const* d_in, const int* in_sizes, int n_in,
                              void* d_out, int out_size, void* d_ws, size_t ws_size,
                              hipStream_t stream) {
    const float* x   = (const float*)d_in[0];
    const float* pr  = (const float*)d_in[2];
    const float* pim = (const float*)d_in[3];
    const float* rr  = (const float*)d_in[4];
    const float* ri  = (const float*)d_in[5];
    float* outp = (float*)d_out;

    char* ws = (char*)d_ws;
    const size_t RA = (size_t)B_N * CIN * T_N * sizeof(float2);  // 16 MB per region
    float2* alpha   = (float2*)ws;            // region A; later reused as out1tmp
    float2* alphaT  = (float2*)(ws + RA);     // region B; later reused as out1T
    float2* o2      = (float2*)(ws + 2 * RA);
    float2* out1tmp = alpha;                  // alpha dead after transpose
    float2* out1T   = alphaT;                 // alphaT dead after k_out2

    hipMemsetAsync(o2, 0, (size_t)B_N * COUT * MODES * sizeof(float2), stream);

    k_fft_fwd     <<<B_N * CIN, 256, 0, stream>>>(x, alpha);
    k_transpose_a <<<CIN * 32, 256, 0, stream>>>(alpha, alphaT);
    k_out1        <<<T_N, 256, 0, stream>>>(alphaT, pr, pim, rr, ri, out1tmp);
    k_out2        <<<CIN * 16, 256, 0, stream>>>((const float4*)alphaT, pr, pim, rr, ri, o2);
    k_transpose_o1<<<32 * 32, 256, 0, stream>>>(out1tmp, out1T);
    k_ifft        <<<B_N * COUT, 256, 0, stream>>>(out1T, outp);
    k_x2          <<<COUT * (T_N / 64), 256, 0, stream>>>(o2, pr, pim, outp);
}